// Round 6
// baseline (278.025 us; speedup 1.0000x reference)
//
#include <hip/hip_runtime.h>
#include <hip/hip_bf16.h>

#define IN_FEATS 768
#define PART_CHUNK 8192
#define SRC_BITS 17
#define SRC_MASK 0x1FFFF

typedef __attribute__((ext_vector_type(8))) short short8v;
typedef __attribute__((ext_vector_type(4))) float f32x4;

__device__ __forceinline__ unsigned short f2bf(float f) {
    union { float f; unsigned int u; } c; c.f = f;
    unsigned int r = (c.u + 0x7FFFu + ((c.u >> 16) & 1u)) >> 16;  // RNE
    return (unsigned short)r;
}
__device__ __forceinline__ float bflo(unsigned int v) {
    union { unsigned int u; float f; } c; c.u = v << 16; return c.f;
}
__device__ __forceinline__ float bfhi(unsigned int v) {
    union { unsigned int u; float f; } c; c.u = v & 0xFFFF0000u; return c.f;
}
__device__ __forceinline__ short8v pack8(float4 p, float4 q) {
    short8v r;
    r[0] = (short)f2bf(p.x); r[1] = (short)f2bf(p.y);
    r[2] = (short)f2bf(p.z); r[3] = (short)f2bf(p.w);
    r[4] = (short)f2bf(q.x); r[5] = (short)f2bf(q.y);
    r[6] = (short)f2bf(q.z); r[7] = (short)f2bf(q.w);
    return r;
}

// ---------------------------------------------------------------------------
// Kernel 1 v2: fused layer-1 linear via bf16 MFMA.
// BK=64 (12 K-steps), double-buffered LDS, ONE barrier per step,
// rows padded to 72 ushorts (144B = 36 dwords -> b128 LDS ops at bank floor).
// ---------------------------------------------------------------------------
__global__ __launch_bounds__(256) void gemm1_kernel(
    const float* __restrict__ x,
    const float* __restrict__ Wn,
    const float* __restrict__ Ws,
    const float* __restrict__ b1,
    unsigned short* __restrict__ hn1b,   // [N,32] bf16 bits
    float* __restrict__ hs1,             // [N,32]
    int N)
{
    __shared__ unsigned short As[2][64][72];
    __shared__ unsigned short Bs[2][64][72];

    const int tid  = threadIdx.x;
    const int lrow = tid >> 2;          // 0..63 (staging row)
    const int lk16 = (tid & 3) * 16;    // 0,16,32,48 (staging k-offset)
    const int row0 = blockIdx.x * 64;

    const int  grow   = row0 + lrow;
    const bool rvalid = (grow < N);
    const float* xrow = x + (size_t)(rvalid ? grow : (N - 1)) * IN_FEATS;
    const float* wrow = (lrow < 32) ? (Wn + (size_t)lrow * IN_FEATS)
                                    : (Ws + (size_t)(lrow - 32) * IN_FEATS);

    const int w    = tid >> 6;          // wave 0..3
    const int l    = tid & 63;
    const int lr16 = l & 15;
    const int lk   = (l >> 4) * 8;      // 0,8,16,24

    f32x4 acc[4];
#pragma unroll
    for (int ct = 0; ct < 4; ++ct) acc[ct] = (f32x4){0.f, 0.f, 0.f, 0.f};

    float4 a0, a1, a2, a3, w0, w1, w2, w3;
    // prologue: load step 0 (k0 = 0)
    a0 = *(const float4*)(xrow + lk16 + 0);
    a1 = *(const float4*)(xrow + lk16 + 4);
    a2 = *(const float4*)(xrow + lk16 + 8);
    a3 = *(const float4*)(xrow + lk16 + 12);
    w0 = *(const float4*)(wrow + lk16 + 0);
    w1 = *(const float4*)(wrow + lk16 + 4);
    w2 = *(const float4*)(wrow + lk16 + 8);
    w3 = *(const float4*)(wrow + lk16 + 12);

    const int NSTEP = IN_FEATS / 64;    // 12
    for (int step = 0; step < NSTEP; ++step) {
        const int buf = step & 1;
        // stage current regs -> LDS (2x b128 per matrix per thread)
        *(short8v*)&As[buf][lrow][lk16]     = pack8(a0, a1);
        *(short8v*)&As[buf][lrow][lk16 + 8] = pack8(a2, a3);
        *(short8v*)&Bs[buf][lrow][lk16]     = pack8(w0, w1);
        *(short8v*)&Bs[buf][lrow][lk16 + 8] = pack8(w2, w3);
        __syncthreads();

        // issue next step's global loads (hidden under MFMA section)
        if (step + 1 < NSTEP) {
            const int k0 = (step + 1) * 64;
            a0 = *(const float4*)(xrow + k0 + lk16 + 0);
            a1 = *(const float4*)(xrow + k0 + lk16 + 4);
            a2 = *(const float4*)(xrow + k0 + lk16 + 8);
            a3 = *(const float4*)(xrow + k0 + lk16 + 12);
            w0 = *(const float4*)(wrow + k0 + lk16 + 0);
            w1 = *(const float4*)(wrow + k0 + lk16 + 4);
            w2 = *(const float4*)(wrow + k0 + lk16 + 8);
            w3 = *(const float4*)(wrow + k0 + lk16 + 12);
        }

        short8v af0 = *(const short8v*)&As[buf][w * 16 + lr16][lk];
        short8v af1 = *(const short8v*)&As[buf][w * 16 + lr16][lk + 32];
#pragma unroll
        for (int ct = 0; ct < 4; ++ct) {
            short8v bf0 = *(const short8v*)&Bs[buf][ct * 16 + lr16][lk];
            acc[ct] = __builtin_amdgcn_mfma_f32_16x16x32_bf16(af0, bf0, acc[ct], 0, 0, 0);
        }
#pragma unroll
        for (int ct = 0; ct < 4; ++ct) {
            short8v bf1 = *(const short8v*)&Bs[buf][ct * 16 + lr16][lk + 32];
            acc[ct] = __builtin_amdgcn_mfma_f32_16x16x32_bf16(af1, bf1, acc[ct], 0, 0, 0);
        }
        // NOTE: no second barrier. Next iteration writes buf^1; all reads of
        // buf^1 (step-1's MFMA) completed before this step's barrier.
    }

    // epilogue: D layout col=lane&15, row=(lane>>4)*4+reg
    const int rbase = row0 + w * 16 + (l >> 4) * 4;
#pragma unroll
    for (int ct = 0; ct < 4; ++ct) {
        const int ncol = ct * 16 + lr16;
        if (ncol < 32) {
#pragma unroll
            for (int j = 0; j < 4; ++j) {
                const int r = rbase + j;
                if (r < N) hn1b[(size_t)r * 32 + ncol] = f2bf(acc[ct][j]);
            }
        } else {
            const int c = ncol - 32;
            const float bias = b1[c];
#pragma unroll
            for (int j = 0; j < 4; ++j) {
                const int r = rbase + j;
                if (r < N) hs1[(size_t)r * 32 + c] = acc[ct][j] + bias;
            }
        }
    }
}

// ---------------------------------------------------------------------------
// CSR build, locality-aware (unchanged from round 5).
// ---------------------------------------------------------------------------
__global__ __launch_bounds__(512) void zero_bcnt_kernel(int* __restrict__ bcnt, int NB)
{
    const int t = threadIdx.x;
    if (t < NB) bcnt[t] = 0;
}

__global__ __launch_bounds__(256) void bucket_hist_kernel(
    const int* __restrict__ dst, int* __restrict__ bcnt, int NB, int E)
{
    __shared__ int h[512];
    const int t = threadIdx.x;
    for (int i = t; i < NB; i += 256) h[i] = 0;
    __syncthreads();
    const int start = blockIdx.x * PART_CHUNK;
    const int end = min(start + PART_CHUNK, E);
    for (int i = start + t; i < end; i += 256)
        atomicAdd(&h[dst[i] >> 8], 1);
    __syncthreads();
    for (int i = t; i < NB; i += 256)
        if (h[i]) atomicAdd(&bcnt[i], h[i]);
}

__global__ __launch_bounds__(512) void bucket_scan_kernel(
    const int* __restrict__ bcnt, int* __restrict__ bstart,
    int* __restrict__ bcursor, int NB, int E)
{
    __shared__ int s[512];
    const int t = threadIdx.x;
    s[t] = (t < NB) ? bcnt[t] : 0;
    __syncthreads();
    for (int off = 1; off < 512; off <<= 1) {
        const int add = (t >= off) ? s[t - off] : 0;
        __syncthreads();
        s[t] += add;
        __syncthreads();
    }
    const int excl = (t > 0) ? s[t - 1] : 0;
    if (t < NB) { bstart[t] = excl; bcursor[t] = excl; }
    if (t == 0) bstart[NB] = E;
}

__global__ __launch_bounds__(256) void partition_kernel(
    const int* __restrict__ src, const int* __restrict__ dst,
    int* __restrict__ bcursor, unsigned int* __restrict__ packed,
    int NB, int E)
{
    __shared__ int hcnt[512];
    __shared__ int hbase[512];
    const int t = threadIdx.x;
    for (int i = t; i < NB; i += 256) hcnt[i] = 0;
    __syncthreads();
    const int start = blockIdx.x * PART_CHUNK;
    const int end = min(start + PART_CHUNK, E);
    for (int i = start + t; i < end; i += 256)
        atomicAdd(&hcnt[dst[i] >> 8], 1);
    __syncthreads();
    for (int i = t; i < NB; i += 256) {
        const int c = hcnt[i];
        hbase[i] = c ? atomicAdd(&bcursor[i], c) : 0;
        hcnt[i] = 0;   // reuse as local cursor
    }
    __syncthreads();
    for (int i = start + t; i < end; i += 256) {
        const int d = dst[i];
        const int b = d >> 8;
        const int p = hbase[b] + atomicAdd(&hcnt[b], 1);
        packed[p] = ((unsigned int)(d & 255) << SRC_BITS) | (unsigned int)src[i];
    }
}

__global__ __launch_bounds__(256) void csr_finalize_kernel(
    const unsigned int* __restrict__ packed, const int* __restrict__ bstart,
    int* __restrict__ rowstart, int* __restrict__ edge_src,
    int NB, int N, int E)
{
    __shared__ int cnt[256];
    __shared__ int sdata[256];
    __shared__ int cur[256];
    const int b = blockIdx.x;
    const int t = threadIdx.x;
    const int base = bstart[b];
    const int endp = bstart[b + 1];

    cnt[t] = 0;
    __syncthreads();
    for (int i = base + t; i < endp; i += 256)
        atomicAdd(&cnt[packed[i] >> SRC_BITS], 1);
    __syncthreads();

    sdata[t] = cnt[t];
    __syncthreads();
    for (int off = 1; off < 256; off <<= 1) {
        const int add = (t >= off) ? sdata[t - off] : 0;
        __syncthreads();
        sdata[t] += add;
        __syncthreads();
    }
    const int excl = (t > 0) ? sdata[t - 1] : 0;
    const int n = (b << 8) + t;
    if (n < N) rowstart[n] = base + excl;
    if (b == NB - 1 && t == 0) rowstart[N] = E;
    cur[t] = base + excl;
    __syncthreads();

    for (int i = base + t; i < endp; i += 256) {
        const unsigned int v = packed[i];
        const int pos = atomicAdd(&cur[v >> SRC_BITS], 1);
        edge_src[pos] = (int)(v & SRC_MASK);
    }
}

// ---------------------------------------------------------------------------
// agg1 fused: 16 nodes/block, 16 lanes/node, bf16x2 gathers. Edge loop
// unrolled x8 (two 4-edge groups in flight) for deeper MLP.
// ---------------------------------------------------------------------------
__global__ __launch_bounds__(256) void agg1_fused_kernel(
    const unsigned short* __restrict__ hn1b, const float* __restrict__ hs1,
    const int* __restrict__ rowstart, const int* __restrict__ edge_src,
    const float* __restrict__ Wn2, const float* __restrict__ Ws2,
    const float* __restrict__ b2,
    unsigned short* __restrict__ hn2b, float* __restrict__ hs2, int N)
{
    __shared__ float w2[16][33];
    __shared__ float bb[8];
    __shared__ float hsm[16][33];

    const int tid = threadIdx.x;
    const int g   = tid >> 4;
    const int ln  = tid & 15;

    w2[tid >> 5][tid & 31]       = Wn2[tid];
    w2[8 + (tid >> 5)][tid & 31] = Ws2[tid];
    if (tid < 8) bb[tid] = b2[tid];

    const unsigned int* hn1u = (const unsigned int*)hn1b;

    const int n = blockIdx.x * 16 + g;
    float sx = 0.f, sy = 0.f;
    int degi = 0;
    if (n < N) {
        const int rs = rowstart[n];
        const int re = rowstart[n + 1];
        degi = re - rs;
        int e = rs;
        for (; e + 8 <= re; e += 8) {
            const int s0 = edge_src[e + 0];
            const int s1 = edge_src[e + 1];
            const int s2 = edge_src[e + 2];
            const int s3 = edge_src[e + 3];
            const int s4 = edge_src[e + 4];
            const int s5 = edge_src[e + 5];
            const int s6 = edge_src[e + 6];
            const int s7 = edge_src[e + 7];
            const unsigned int v0 = hn1u[(size_t)s0 * 16 + ln];
            const unsigned int v1 = hn1u[(size_t)s1 * 16 + ln];
            const unsigned int v2 = hn1u[(size_t)s2 * 16 + ln];
            const unsigned int v3 = hn1u[(size_t)s3 * 16 + ln];
            const unsigned int v4 = hn1u[(size_t)s4 * 16 + ln];
            const unsigned int v5 = hn1u[(size_t)s5 * 16 + ln];
            const unsigned int v6 = hn1u[(size_t)s6 * 16 + ln];
            const unsigned int v7 = hn1u[(size_t)s7 * 16 + ln];
            sx += ((bflo(v0) + bflo(v1)) + (bflo(v2) + bflo(v3)))
                + ((bflo(v4) + bflo(v5)) + (bflo(v6) + bflo(v7)));
            sy += ((bfhi(v0) + bfhi(v1)) + (bfhi(v2) + bfhi(v3)))
                + ((bfhi(v4) + bfhi(v5)) + (bfhi(v6) + bfhi(v7)));
        }
        for (; e < re; ++e) {
            const unsigned int v = hn1u[(size_t)edge_src[e] * 16 + ln];
            sx += bflo(v); sy += bfhi(v);
        }
        const float inv = 1.0f / fmaxf((float)degi, 1.0f);
        const float2 hs = *(const float2*)(hs1 + (size_t)n * 32 + 2 * ln);
        hsm[g][2 * ln + 0] = fmaxf(hs.x + sx * inv, 0.0f);
        hsm[g][2 * ln + 1] = fmaxf(hs.y + sy * inv, 0.0f);
    }
    __syncthreads();

    if (n < N) {
        const float* wrow = w2[ln];
        const float* hv   = hsm[g];
        float acc = 0.0f;
#pragma unroll
        for (int k = 0; k < 32; ++k) acc += wrow[k] * hv[k];
        if (ln < 8) hn2b[(size_t)n * 8 + ln] = f2bf(acc);
        else        hs2[(size_t)n * 8 + (ln - 8)] = acc + bb[ln - 8];
    }
}

// ---------------------------------------------------------------------------
// agg2 fused (unchanged): out = hs2 + mean(gather hn2b)
// ---------------------------------------------------------------------------
__global__ __launch_bounds__(256) void agg2_fused_kernel(
    const unsigned short* __restrict__ hn2b, const float* __restrict__ hs2,
    const int* __restrict__ rowstart, const int* __restrict__ edge_src,
    float* __restrict__ out, int N)
{
    const int tid  = threadIdx.x;
    const int g    = tid >> 4;
    const int ln   = tid & 15;
    const int slot = ln >> 2;
    const int q    = ln & 3;

    const unsigned int* hn2u = (const unsigned int*)hn2b;

    const int n = blockIdx.x * 16 + g;
    float sx = 0.f, sy = 0.f;
    int degi = 0;
    if (n < N) {
        const int rs = rowstart[n];
        const int re = rowstart[n + 1];
        degi = re - rs;
        for (int e = rs + slot; e < re; e += 4) {
            const unsigned int v = hn2u[(size_t)edge_src[e] * 4 + q];
            sx += bflo(v); sy += bfhi(v);
        }
    }
    sx += __shfl_xor(sx, 4, 64);  sy += __shfl_xor(sy, 4, 64);
    sx += __shfl_xor(sx, 8, 64);  sy += __shfl_xor(sy, 8, 64);

    if (n < N && slot == 0) {
        const float inv = 1.0f / fmaxf((float)degi, 1.0f);
        const float2 s = *(const float2*)(hs2 + (size_t)n * 8 + 2 * q);
        float2 o;
        o.x = s.x + sx * inv;
        o.y = s.y + sy * inv;
        *(float2*)(out + (size_t)n * 8 + 2 * q) = o;
    }
}

extern "C" void kernel_launch(void* const* d_in, const int* in_sizes, int n_in,
                              void* d_out, int out_size, void* d_ws, size_t ws_size,
                              hipStream_t stream)
{
    const float* feats = (const float*)d_in[0];
    const int*   src   = (const int*)d_in[1];
    const int*   dst   = (const int*)d_in[2];
    const float* Ws1   = (const float*)d_in[3];
    const float* Wn1   = (const float*)d_in[4];
    const float* b1    = (const float*)d_in[5];
    const float* Ws2   = (const float*)d_in[6];
    const float* Wn2   = (const float*)d_in[7];
    const float* b2    = (const float*)d_in[8];
    float* out = (float*)d_out;

    const int N = in_sizes[0] / IN_FEATS;   // 100000
    const int E = in_sizes[1];              // 3200000
    const int NB = (N + 255) >> 8;          // 391 buckets of 256 nodes

    // Workspace layout
    char* ws = (char*)d_ws;
    const size_t N32 = (size_t)N * 32;
    const size_t N8  = (size_t)N * 8;
    unsigned short* hn1b = (unsigned short*)ws;            // [N,32] bf16
    ws += ((N32 * 2 + 255) / 256) * 256;
    float* hs1 = (float*)ws;                               // [N,32] f32
    ws += ((N32 * 4 + 255) / 256) * 256;
    unsigned short* hn2b = (unsigned short*)ws;            // [N,8] bf16
    ws += ((N8 * 2 + 255) / 256) * 256;
    float* hs2 = (float*)ws;                               // [N,8] f32
    ws += ((N8 * 4 + 255) / 256) * 256;
    int* rowstart = (int*)ws;                              // [N+1]
    ws += (((size_t)(N + 1) * 4 + 255) / 256) * 256;
    int* bcnt = (int*)ws;                                  // [NB]
    ws += 512 * 4;
    int* bstart = (int*)ws;                                // [NB+1]
    ws += 520 * 4;
    int* bcursor = (int*)ws;                               // [NB]
    ws += 512 * 4;
    unsigned int* packed = (unsigned int*)ws;              // [E]
    ws += (((size_t)E * 4 + 255) / 256) * 256;
    int* edge_src = (int*)ws;                              // [E]

    const int nbPart = (E + PART_CHUNK - 1) / PART_CHUNK;

    // --- CSR build (locality-aware two-level partition) ---
    zero_bcnt_kernel<<<1, 512, 0, stream>>>(bcnt, NB);
    bucket_hist_kernel<<<nbPart, 256, 0, stream>>>(dst, bcnt, NB, E);
    bucket_scan_kernel<<<1, 512, 0, stream>>>(bcnt, bstart, bcursor, NB, E);
    partition_kernel<<<nbPart, 256, 0, stream>>>(src, dst, bcursor, packed, NB, E);
    csr_finalize_kernel<<<NB, 256, 0, stream>>>(packed, bstart, rowstart,
                                                edge_src, NB, N, E);

    // --- layer-1 fused GEMM (bf16 MFMA, v2) ---
    gemm1_kernel<<<(N + 63) / 64, 256, 0, stream>>>(feats, Wn1, Ws1, b1,
                                                    hn1b, hs1, N);

    // --- layer-1 aggregation + finish + layer-2 linear ---
    agg1_fused_kernel<<<(N + 15) / 16, 256, 0, stream>>>(
        hn1b, hs1, rowstart, edge_src, Wn2, Ws2, b2, hn2b, hs2, N);

    // --- layer-2 aggregation + final combine ---
    agg2_fused_kernel<<<(N + 15) / 16, 256, 0, stream>>>(
        hn2b, hs2, rowstart, edge_src, out, N);
}